// Round 20
// baseline (118.711 us; speedup 1.0000x reference)
//
#include <hip/hip_runtime.h>

#define NWIN 4096
#define DIMC 128
#define NTOK 49
#define NBLK 512                        // persistent blocks: 2/CU, 4 pairs each
#define QK_SCALE 0.17677669529663689f   // 32^-0.5
#define LOG2E 1.4426950408889634f

typedef __attribute__((ext_vector_type(8))) short vs8;
typedef __attribute__((ext_vector_type(4))) float vf4;
typedef __attribute__((ext_vector_type(2))) unsigned vu2;
typedef __attribute__((ext_vector_type(4))) _Float16 vh4;
typedef __attribute__((ext_vector_type(8))) _Float16 vh8;
typedef __attribute__((ext_vector_type(2))) __fp16 vp2;

#define NO_CSE() asm volatile("" ::: "memory")
#define SWZ(row) (((row) & 15) << 4)

__device__ __forceinline__ unsigned cvtpk(float a, float b) {
  unsigned r;
  asm("v_cvt_pk_bf16_f32 %0, %1, %2" : "=v"(r) : "v"(a), "v"(b));
  return r;
}

__device__ __forceinline__ float exp2f_raw(float x) {
  float r;
  asm("v_exp_f32 %0, %1" : "=v"(r) : "v"(x));
  return r;
}

__device__ __forceinline__ vh4 pack4h(float a0, float a1, float a2, float a3) {
  union { vh4 v; vp2 h[2]; } u;
  u.h[0] = __builtin_amdgcn_cvt_pkrtz(a0, a1);
  u.h[1] = __builtin_amdgcn_cvt_pkrtz(a2, a3);
  return u.v;
}

__device__ __forceinline__ vh8 cat8(vh4 a, vh4 b) {
  union { vh8 v8; vh4 v4[2]; } u;
  u.v4[0] = a; u.v4[1] = b;
  return u.v8;
}

__device__ __forceinline__ vf4 unpack_bf4(vu2 b) {
  union { unsigned u; float f; } a0, a1, a2, a3;
  a0.u = b[0] << 16; a1.u = b[0] & 0xffff0000u;
  a2.u = b[1] << 16; a3.u = b[1] & 0xffff0000u;
  return (vf4){a0.f, a1.f, a2.f, a3.f};
}

__device__ __forceinline__ short f2bf(float f) {
  union { float f; unsigned u; } x; x.f = f;
  unsigned r = x.u + 0x7fffu + ((x.u >> 16) & 1u);
  return (short)(r >> 16);
}

// ---------------- prep ----------------
__global__ void prep_kernel(const float* __restrict__ qkv_w, const float* __restrict__ proj_w,
                            const float* __restrict__ bias_table, const int* __restrict__ rel_index,
                            short* __restrict__ qkv_wb, short* __restrict__ proj_wb,
                            short* __restrict__ bias_bf) {
  int i = blockIdx.x * 256 + threadIdx.x;
  if (i < 49152) qkv_wb[i] = f2bf(qkv_w[i]);
  int j = i - 49152;
  if (j >= 0 && j < 16384) proj_wb[j] = f2bf(proj_w[j]);
  int k = i - 65536;
  if (k >= 0 && k < 16384) {
    int h = k >> 12, rc = k & 4095, r = rc >> 6, c = rc & 63;
    float v = -1e30f;
    if (r < NTOK && c < NTOK) v = bias_table[rel_index[r * NTOK + c] * 4 + h];
    bias_bf[k] = f2bf(v * LOG2E);
  }
}

// ---------------- fused window attention — persistent blocks, LDS double-buffer ----------------
// R20 (base = R19, 77.4us): 512 persistent blocks (2/CU at 64KB LDS), each loops
// over 4 window-pairs. Next pair's x loads issued after the X-dead barrier
// (latency hides under attention); cvt+ds_write into the OTHER 32KB buffer before
// the O-barrier. Cross-iter hazards covered by the existing 3 barriers. Weight
// loads L1-hot after iter 0; 4x fewer launches; cold-start prologue paid once.
// Retained: QK-fused GEMM1 passes, GEMM2 ci-fusion, exp2 path, 4-bit swizzle,
// setprio, cin prefetch, no-max softmax, per-head norm at O-write, C-in biases.
__launch_bounds__(256)
__global__ void win_attn(const float* __restrict__ x,
                         const float* __restrict__ qkv_b,
                         const float* __restrict__ proj_b,
                         const short* __restrict__ qkv_wb,
                         const short* __restrict__ proj_wb,
                         const short* __restrict__ bias_bf,
                         float* __restrict__ out) {
  __shared__ __align__(16) char lds[65536];

  const int tid  = threadIdx.x;
  const int lane = tid & 63;
  const int w    = tid >> 6;
  const int l15  = lane & 15;
  const int g    = lane >> 4;
  const float QSC2 = QK_SCALE * LOG2E;
  const short* bpb = bias_bf + w * 4096;

  int srow[4], sc16[4], soff[4];
#pragma unroll
  for (int it = 0; it < 4; ++it) {
    int chunk = tid + it * 256;
    srow[it] = chunk >> 4; sc16[it] = chunk & 15;
    soff[it] = srow[it] * 256 + ((sc16[it] * 16) ^ SWZ(srow[it]));
  }

  // ---- QK-dt0 weights (persistent slots, reloaded each iter at loop bottom) ----
  vs8 bwQ[4], bwK[4];
  vf4 qbQ, qbK;
  {
    const short* wrQ = qkv_wb + ((2 * w) * 16 + l15) * DIMC;
    const short* wrK = qkv_wb + ((8 + 2 * w) * 16 + l15) * DIMC;
#pragma unroll
    for (int kk = 0; kk < 4; ++kk) {
      bwQ[kk] = *(const vs8*)(wrQ + kk * 32 + g * 8);
      bwK[kk] = *(const vs8*)(wrK + kk * 32 + g * 8);
    }
    qbQ = *(const vf4*)(qkv_b + (2 * w) * 16 + g * 4);
    qbK = *(const vf4*)(qkv_b + (8 + 2 * w) * 16 + g * 4);
  }

  // ---- initial stage: pair blockIdx.x -> buffer 0 ----
  {
    const float* xwA = x + (size_t)(2 * blockIdx.x) * (NTOK * DIMC);
    const float* xwB = xwA + NTOK * DIMC;
#pragma unroll
    for (int it = 0; it < 4; ++it) {
      union { vs8 s; unsigned u[4]; } pA, pB;
      if (srow[it] < NTOK) {
        const float* sA = xwA + srow[it] * DIMC + sc16[it] * 8;
        const float* sB = xwB + srow[it] * DIMC + sc16[it] * 8;
        vf4 a0 = *(const vf4*)sA, b0 = *(const vf4*)(sA + 4);
        vf4 a1 = *(const vf4*)sB, b1 = *(const vf4*)(sB + 4);
        pA.u[0] = cvtpk(a0.x, a0.y); pA.u[1] = cvtpk(a0.z, a0.w);
        pA.u[2] = cvtpk(b0.x, b0.y); pA.u[3] = cvtpk(b0.z, b0.w);
        pB.u[0] = cvtpk(a1.x, a1.y); pB.u[1] = cvtpk(a1.z, a1.w);
        pB.u[2] = cvtpk(b1.x, b1.y); pB.u[3] = cvtpk(b1.z, b1.w);
      } else {
        pA.u[0] = pA.u[1] = pA.u[2] = pA.u[3] = 0u;
        pB.u[0] = pB.u[1] = pB.u[2] = pB.u[3] = 0u;
      }
      *(vs8*)(lds + soff[it]) = pA.s;
      *(vs8*)(lds + 16384 + soff[it]) = pB.s;
    }
  }

  for (int it = 0; it < 4; ++it) {
    const int winA = 2 * (blockIdx.x + it * NBLK);
    char* const ldsA = lds + ((it & 1) << 15);
    char* const ldsB = ldsA + 16384;
    char* const nxtA = lds + (((it + 1) & 1) << 15);
    char* const nxtB = nxtA + 16384;
    __syncthreads();  // barrier-1: staged X visible; prev iter's GEMM2 done with nxt

    // ---- GEMM1: 4 passes (QK-dt0, V-dt0, QK-dt1, V-dt1), shared frag reads ----
    vh4 qB[2][4], qBB[2][4], kA[2][4], kAB[2][4], vA[2][4], vAB[2][4];
    vs8 bwV[4];
    float bvV;
#pragma unroll
    for (int dt = 0; dt < 2; ++dt) {
      {
        const int cV = 16 + 2 * w + dt;
        const short* wr = qkv_wb + (cV * 16 + l15) * DIMC;
#pragma unroll
        for (int kk = 0; kk < 4; ++kk) bwV[kk] = *(const vs8*)(wr + kk * 32 + g * 8);
        bvV = qkv_b[cV * 16 + l15];
      }
      NO_CSE();
      {  // QK pass
        vf4 aQ[2][4], aK[2][4];
#pragma unroll
        for (int tr = 0; tr < 4; ++tr) {
          aQ[0][tr] = qbQ; aQ[1][tr] = qbQ;
          aK[0][tr] = qbK; aK[1][tr] = qbK;
        }
        __builtin_amdgcn_s_setprio(1);
#pragma unroll
        for (int kk = 0; kk < 4; ++kk)
#pragma unroll
          for (int tr = 0; tr < 4; ++tr) {
            int row = tr * 16 + l15;
            int off = row * 256 + ((kk * 64 + g * 16) ^ SWZ(row));
            vs8 fA = *(const vs8*)(ldsA + off);
            vs8 fB = *(const vs8*)(ldsB + off);
            aQ[0][tr] = __builtin_amdgcn_mfma_f32_16x16x32_bf16(bwQ[kk], fA, aQ[0][tr], 0, 0, 0);
            aK[0][tr] = __builtin_amdgcn_mfma_f32_16x16x32_bf16(bwK[kk], fA, aK[0][tr], 0, 0, 0);
            aQ[1][tr] = __builtin_amdgcn_mfma_f32_16x16x32_bf16(bwQ[kk], fB, aQ[1][tr], 0, 0, 0);
            aK[1][tr] = __builtin_amdgcn_mfma_f32_16x16x32_bf16(bwK[kk], fB, aK[1][tr], 0, 0, 0);
          }
        __builtin_amdgcn_s_setprio(0);
#pragma unroll
        for (int tr = 0; tr < 4; ++tr) {
          qB[dt][tr]  = pack4h(aQ[0][tr][0] * QSC2, aQ[0][tr][1] * QSC2, aQ[0][tr][2] * QSC2, aQ[0][tr][3] * QSC2);
          qBB[dt][tr] = pack4h(aQ[1][tr][0] * QSC2, aQ[1][tr][1] * QSC2, aQ[1][tr][2] * QSC2, aQ[1][tr][3] * QSC2);
          kA[dt][tr]  = pack4h(aK[0][tr][0], aK[0][tr][1], aK[0][tr][2], aK[0][tr][3]);
          kAB[dt][tr] = pack4h(aK[1][tr][0], aK[1][tr][1], aK[1][tr][2], aK[1][tr][3]);
        }
      }
      if (dt == 0) {  // prefetch QK-dt1 weights (hides under V pass)
        const short* wrQ = qkv_wb + ((2 * w + 1) * 16 + l15) * DIMC;
        const short* wrK = qkv_wb + ((8 + 2 * w + 1) * 16 + l15) * DIMC;
#pragma unroll
        for (int kk = 0; kk < 4; ++kk) {
          bwQ[kk] = *(const vs8*)(wrQ + kk * 32 + g * 8);
          bwK[kk] = *(const vs8*)(wrK + kk * 32 + g * 8);
        }
        qbQ = *(const vf4*)(qkv_b + (2 * w + 1) * 16 + g * 4);
        qbK = *(const vf4*)(qkv_b + (8 + 2 * w + 1) * 16 + g * 4);
      }
      NO_CSE();
      {  // V pass
        vf4 aV[2][4];
#pragma unroll
        for (int tr = 0; tr < 4; ++tr) {
          aV[0][tr] = (vf4){bvV, bvV, bvV, bvV};
          aV[1][tr] = aV[0][tr];
        }
        __builtin_amdgcn_s_setprio(1);
#pragma unroll
        for (int kk = 0; kk < 4; ++kk)
#pragma unroll
          for (int tr = 0; tr < 4; ++tr) {
            int row = tr * 16 + l15;
            int off = row * 256 + ((kk * 64 + g * 16) ^ SWZ(row));
            vs8 fA = *(const vs8*)(ldsA + off);
            vs8 fB = *(const vs8*)(ldsB + off);
            aV[0][tr] = __builtin_amdgcn_mfma_f32_16x16x32_bf16(fA, bwV[kk], aV[0][tr], 0, 0, 0);
            aV[1][tr] = __builtin_amdgcn_mfma_f32_16x16x32_bf16(fB, bwV[kk], aV[1][tr], 0, 0, 0);
          }
        __builtin_amdgcn_s_setprio(0);
#pragma unroll
        for (int tr = 0; tr < 4; ++tr) {
          vA[dt][tr]  = pack4h(aV[0][tr][0], aV[0][tr][1], aV[0][tr][2], aV[0][tr][3]);
          vAB[dt][tr] = pack4h(aV[1][tr][0], aV[1][tr][1], aV[1][tr][2], aV[1][tr][3]);
        }
      }
    }

    // ---- trQ=0 attention bias issued before the X-dead barrier ----
    vu2 cinC[4];
#pragma unroll
    for (int tcK = 0; tcK < 4; ++tcK)
      cinC[tcK] = *(const vu2*)(bpb + l15 * 64 + tcK * 16 + g * 4);
    __syncthreads();  // barrier-2: X dead in both halves

    // ---- issue NEXT pair's x loads (latency hides under attention) ----
    vf4 naA[4], nbA[4], naB[4], nbB[4];
    const bool more = (it < 3);
    if (more) {
      const float* xwA = x + (size_t)(2 * (blockIdx.x + (it + 1) * NBLK)) * (NTOK * DIMC);
      const float* xwB = xwA + NTOK * DIMC;
#pragma unroll
      for (int k2 = 0; k2 < 4; ++k2) {
        if (srow[k2] < NTOK) {
          const float* sA = xwA + srow[k2] * DIMC + sc16[k2] * 8;
          const float* sB = xwB + srow[k2] * DIMC + sc16[k2] * 8;
          naA[k2] = *(const vf4*)sA; nbA[k2] = *(const vf4*)(sA + 4);
          naB[k2] = *(const vf4*)sB; nbB[k2] = *(const vf4*)(sB + 4);
        }
      }
    }

    // ---- attention fused per q-row-tile ----
#pragma unroll
    for (int trQ = 0; trQ < 4; ++trQ) {
      const int q = trQ * 16 + l15;
      vu2 cinN[4];
      if (trQ < 3) {
#pragma unroll
        for (int tcK = 0; tcK < 4; ++tcK)
          cinN[tcK] = *(const vu2*)(bpb + (q + 16) * 64 + tcK * 16 + g * 4);
      }
      const vh8 q8A = cat8(qB[0][trQ], qB[1][trQ]);
      const vh8 q8B = cat8(qBB[0][trQ], qBB[1][trQ]);
      vf4 sA[4], sB[4];
      __builtin_amdgcn_s_setprio(1);
#pragma unroll
      for (int tcK = 0; tcK < 4; ++tcK) {
        vf4 cin = unpack_bf4(cinC[tcK]);
        sA[tcK] = __builtin_amdgcn_mfma_f32_16x16x32_f16(cat8(kA[0][tcK], kA[1][tcK]), q8A, cin, 0, 0, 0);
        sB[tcK] = __builtin_amdgcn_mfma_f32_16x16x32_f16(cat8(kAB[0][tcK], kAB[1][tcK]), q8B, cin, 0, 0, 0);
      }
      __builtin_amdgcn_s_setprio(0);
      float sumA = 0.f, sumB = 0.f;
#pragma unroll
      for (int tcK = 0; tcK < 4; ++tcK)
#pragma unroll
        for (int r = 0; r < 4; ++r) {
          float eA = exp2f_raw(sA[tcK][r]); sA[tcK][r] = eA; sumA += eA;
          float eB = exp2f_raw(sB[tcK][r]); sB[tcK][r] = eB; sumB += eB;
        }
      sumA += __shfl_xor(sumA, 16, 64);
      sumB += __shfl_xor(sumB, 16, 64);
      sumA += __shfl_xor(sumA, 32, 64);
      sumB += __shfl_xor(sumB, 32, 64);
      float ivA = 1.0f / sumA, ivB = 1.0f / sumB;
      vh4 pA[4], pB[4];
#pragma unroll
      for (int tcK = 0; tcK < 4; ++tcK) {
        pA[tcK] = pack4h(sA[tcK][0], sA[tcK][1], sA[tcK][2], sA[tcK][3]);
        pB[tcK] = pack4h(sB[tcK][0], sB[tcK][1], sB[tcK][2], sB[tcK][3]);
      }
      vf4 o0A = (vf4){0.f,0.f,0.f,0.f}, o1A = o0A, o0B = o0A, o1B = o0A;
      __builtin_amdgcn_s_setprio(1);
#pragma unroll
      for (int tp = 0; tp < 2; ++tp) {
        const vh8 p8A = cat8(pA[2 * tp], pA[2 * tp + 1]);
        const vh8 p8B = cat8(pB[2 * tp], pB[2 * tp + 1]);
        o0A = __builtin_amdgcn_mfma_f32_16x16x32_f16(cat8(vA[0][2 * tp], vA[0][2 * tp + 1]), p8A, o0A, 0, 0, 0);
        o0B = __builtin_amdgcn_mfma_f32_16x16x32_f16(cat8(vAB[0][2 * tp], vAB[0][2 * tp + 1]), p8B, o0B, 0, 0, 0);
        o1A = __builtin_amdgcn_mfma_f32_16x16x32_f16(cat8(vA[1][2 * tp], vA[1][2 * tp + 1]), p8A, o1A, 0, 0, 0);
        o1B = __builtin_amdgcn_mfma_f32_16x16x32_f16(cat8(vAB[1][2 * tp], vAB[1][2 * tp + 1]), p8B, o1B, 0, 0, 0);
      }
      __builtin_amdgcn_s_setprio(0);
      {
        int db0 = (w * 32 + g * 4) * 2;
        int db1 = (w * 32 + 16 + g * 4) * 2;
        int o0 = q * 256 + (db0 ^ SWZ(q));
        int o1 = q * 256 + (db1 ^ SWZ(q));
        vu2 p;
        p[0] = cvtpk(o0A[0] * ivA, o0A[1] * ivA); p[1] = cvtpk(o0A[2] * ivA, o0A[3] * ivA);
        *(vu2*)(ldsA + o0) = p;
        p[0] = cvtpk(o1A[0] * ivA, o1A[1] * ivA); p[1] = cvtpk(o1A[2] * ivA, o1A[3] * ivA);
        *(vu2*)(ldsA + o1) = p;
        p[0] = cvtpk(o0B[0] * ivB, o0B[1] * ivB); p[1] = cvtpk(o0B[2] * ivB, o0B[3] * ivB);
        *(vu2*)(ldsB + o0) = p;
        p[0] = cvtpk(o1B[0] * ivB, o1B[1] * ivB); p[1] = cvtpk(o1B[2] * ivB, o1B[3] * ivB);
        *(vu2*)(ldsB + o1) = p;
      }
#pragma unroll
      for (int tcK = 0; tcK < 4; ++tcK) cinC[tcK] = cinN[tcK];
    }

    // ---- stage NEXT pair into the other buffer (before the O barrier) ----
    if (more) {
#pragma unroll
      for (int k2 = 0; k2 < 4; ++k2) {
        union { vs8 s; unsigned u[4]; } pA, pB;
        if (srow[k2] < NTOK) {
          pA.u[0] = cvtpk(naA[k2].x, naA[k2].y); pA.u[1] = cvtpk(naA[k2].z, naA[k2].w);
          pA.u[2] = cvtpk(nbA[k2].x, nbA[k2].y); pA.u[3] = cvtpk(nbA[k2].z, nbA[k2].w);
          pB.u[0] = cvtpk(naB[k2].x, naB[k2].y); pB.u[1] = cvtpk(naB[k2].z, naB[k2].w);
          pB.u[2] = cvtpk(nbB[k2].x, nbB[k2].y); pB.u[3] = cvtpk(nbB[k2].z, nbB[k2].w);
        } else {
          pA.u[0] = pA.u[1] = pA.u[2] = pA.u[3] = 0u;
          pB.u[0] = pB.u[1] = pB.u[2] = pB.u[3] = 0u;
        }
        *(vs8*)(nxtA + soff[k2]) = pA.s;
        *(vs8*)(nxtB + soff[k2]) = pB.s;
      }
    }

    // ---- GEMM2 weights/bias (L1-hot after iter 0) loaded before barrier ----
    vs8 bw2[2][4];
    vf4 pb2[2];
#pragma unroll
    for (int ci = 0; ci < 2; ++ci) {
      int ct = w + ci * 4;
      const short* wr = proj_wb + (ct * 16 + l15) * DIMC;
#pragma unroll
      for (int kk = 0; kk < 4; ++kk) bw2[ci][kk] = *(const vs8*)(wr + kk * 32 + g * 8);
      pb2[ci] = *(const vf4*)(proj_b + ct * 16 + g * 4);
    }
    __syncthreads();  // barrier-3: O visible; next-pair staging done

    // ---- GEMM2 (swapped), both ci fused ----
    float* outA = out + (size_t)winA * (NTOK * DIMC);
    float* outB = outA + NTOK * DIMC;
    {
      NO_CSE();
      vf4 acc[2][2][4];
#pragma unroll
      for (int ci = 0; ci < 2; ++ci)
#pragma unroll
        for (int tr = 0; tr < 4; ++tr) { acc[ci][0][tr] = pb2[ci]; acc[ci][1][tr] = pb2[ci]; }
      __builtin_amdgcn_s_setprio(1);
#pragma unroll
      for (int kk = 0; kk < 4; ++kk)
#pragma unroll
        for (int tr = 0; tr < 4; ++tr) {
          int row = tr * 16 + l15;
          int off = row * 256 + ((kk * 64 + g * 16) ^ SWZ(row));
          vs8 fA = *(const vs8*)(ldsA + off);
          vs8 fB = *(const vs8*)(ldsB + off);
          acc[0][0][tr] = __builtin_amdgcn_mfma_f32_16x16x32_bf16(bw2[0][kk], fA, acc[0][0][tr], 0, 0, 0);
          acc[1][0][tr] = __builtin_amdgcn_mfma_f32_16x16x32_bf16(bw2[1][kk], fA, acc[1][0][tr], 0, 0, 0);
          acc[0][1][tr] = __builtin_amdgcn_mfma_f32_16x16x32_bf16(bw2[0][kk], fB, acc[0][1][tr], 0, 0, 0);
          acc[1][1][tr] = __builtin_amdgcn_mfma_f32_16x16x32_bf16(bw2[1][kk], fB, acc[1][1][tr], 0, 0, 0);
        }
      __builtin_amdgcn_s_setprio(0);
#pragma unroll
      for (int ci = 0; ci < 2; ++ci) {
        int ct = w + ci * 4;
#pragma unroll
        for (int tr = 0; tr < 4; ++tr) {
          int token = tr * 16 + l15;
          if (token < NTOK) {
            *(vf4*)(outA + token * DIMC + ct * 16 + g * 4) = acc[ci][0][tr];
            *(vf4*)(outB + token * DIMC + ct * 16 + g * 4) = acc[ci][1][tr];
          }
        }
      }
    }

    // ---- reload QK-dt0 weights for next iteration (L1-hot) ----
    if (more) {
      const short* wrQ = qkv_wb + ((2 * w) * 16 + l15) * DIMC;
      const short* wrK = qkv_wb + ((8 + 2 * w) * 16 + l15) * DIMC;
#pragma unroll
      for (int kk = 0; kk < 4; ++kk) {
        bwQ[kk] = *(const vs8*)(wrQ + kk * 32 + g * 8);
        bwK[kk] = *(const vs8*)(wrK + kk * 32 + g * 8);
      }
      qbQ = *(const vf4*)(qkv_b + (2 * w) * 16 + g * 4);
      qbK = *(const vf4*)(qkv_b + (8 + 2 * w) * 16 + g * 4);
    }
  }
}

extern "C" void kernel_launch(void* const* d_in, const int* in_sizes, int n_in,
                              void* d_out, int out_size, void* d_ws, size_t ws_size,
                              hipStream_t stream) {
  const float* x          = (const float*)d_in[0];
  const float* qkv_w      = (const float*)d_in[1];
  const float* qkv_b      = (const float*)d_in[2];
  const float* proj_w     = (const float*)d_in[3];
  const float* proj_b     = (const float*)d_in[4];
  const float* bias_table = (const float*)d_in[5];
  const int*   rel_index  = (const int*)d_in[6];
  float* out = (float*)d_out;

  short* qkv_wb   = (short*)d_ws;                      // 49152 bf16
  short* proj_wb  = (short*)((char*)d_ws + 98304);     // 16384 bf16
  short* bias_bf  = (short*)((char*)d_ws + 131072);    // 4*64*64 bf16 = 32KB

  prep_kernel<<<320, 256, 0, stream>>>(qkv_w, proj_w, bias_table, rel_index,
                                       qkv_wb, proj_wb, bias_bf);
  win_attn<<<NBLK, 256, 0, stream>>>(x, qkv_b, proj_b, qkv_wb, proj_wb, bias_bf, out);
}

// Round 21
// 77.086 us; speedup vs baseline: 1.5400x; 1.5400x over previous
//
#include <hip/hip_runtime.h>

#define NWIN 4096
#define NTOK 49
#define DIMC 128
#define QK_SCALE 0.17677669529663689f   // 32^-0.5
#define LOG2E 1.4426950408889634f

typedef __attribute__((ext_vector_type(8))) short vs8;        // 8 bf16 (4 VGPRs)
typedef __attribute__((ext_vector_type(4))) float vf4;
typedef __attribute__((ext_vector_type(2))) unsigned vu2;     // 2 packed bf16x2
typedef __attribute__((ext_vector_type(4))) _Float16 vh4;     // 4 f16 (2 VGPRs)
typedef __attribute__((ext_vector_type(8))) _Float16 vh8;     // 8 f16 (4 VGPRs) — K=32 MFMA operand
typedef __attribute__((ext_vector_type(2))) __fp16 vp2;       // cvt_pkrtz result type

#define NO_CSE() asm volatile("" ::: "memory")
// 4-bit row swizzle (R16: bank conflicts 8.9M -> 0.52M)
#define SWZ(row) (((row) & 15) << 4)

__device__ __forceinline__ unsigned cvtpk(float a, float b) {  // 2xf32 -> packed bf16x2
  unsigned r;
  asm("v_cvt_pk_bf16_f32 %0, %1, %2" : "=v"(r) : "v"(a), "v"(b));
  return r;
}

__device__ __forceinline__ float exp2f_raw(float x) {  // 2^x
  float r;
  asm("v_exp_f32 %0, %1" : "=v"(r) : "v"(x));
  return r;
}

__device__ __forceinline__ vh4 pack4h(float a0, float a1, float a2, float a3) {
  union { vh4 v; vp2 h[2]; } u;
  u.h[0] = __builtin_amdgcn_cvt_pkrtz(a0, a1);
  u.h[1] = __builtin_amdgcn_cvt_pkrtz(a2, a3);
  return u.v;
}

__device__ __forceinline__ vh8 cat8(vh4 a, vh4 b) {
  union { vh8 v8; vh4 v4[2]; } u;
  u.v4[0] = a; u.v4[1] = b;
  return u.v8;
}

__device__ __forceinline__ vf4 unpack_bf4(vu2 b) {  // 4 packed bf16 -> vf4
  union { unsigned u; float f; } a0, a1, a2, a3;
  a0.u = b[0] << 16; a1.u = b[0] & 0xffff0000u;
  a2.u = b[1] << 16; a3.u = b[1] & 0xffff0000u;
  return (vf4){a0.f, a1.f, a2.f, a3.f};
}

__device__ __forceinline__ short f2bf(float f) {
  union { float f; unsigned u; } x; x.f = f;
  unsigned r = x.u + 0x7fffu + ((x.u >> 16) & 1u);
  return (short)(r >> 16);
}

// ---------------- prep: weights->bf16, bias*log2e -> padded bf16 [4][64][64] ----------------
__global__ void prep_kernel(const float* __restrict__ qkv_w, const float* __restrict__ proj_w,
                            const float* __restrict__ bias_table, const int* __restrict__ rel_index,
                            short* __restrict__ qkv_wb, short* __restrict__ proj_wb,
                            short* __restrict__ bias_bf) {
  int i = blockIdx.x * 256 + threadIdx.x;
  if (i < 49152) qkv_wb[i] = f2bf(qkv_w[i]);
  int j = i - 49152;
  if (j >= 0 && j < 16384) proj_wb[j] = f2bf(proj_w[j]);
  int k = i - 65536;
  if (k >= 0 && k < 16384) {
    int h = k >> 12, rc = k & 4095, r = rc >> 6, c = rc & 63;
    float v = -1e30f;
    if (r < NTOK && c < NTOK) v = bias_table[rel_index[r * NTOK + c] * 4 + h];
    bias_bf[k] = f2bf(v * LOG2E);   // fold log2e: softmax uses 2^x directly
  }
}

// ---------------- fused window attention — TWO windows, TWO barriers ----------------
// R21 (base = R19, 77.4us): O gets its own 32KB LDS region (no X overlay) ->
// the X-dead barrier (barrier-2) is gone. Waves now run barrier-free from the
// staging barrier to the pre-GEMM2 barrier (longest stretch), so fast waves
// drift/overlap instead of re-aligning between GEMM1 and attention.
// LDS 64KB (caps 2 blocks/CU; measured residency ~1.6 so cap shouldn't bind).
// Retained: QK-fused GEMM1 passes, GEMM2 ci-fusion, exp2 path, 4-bit swizzle,
// setprio, cin prefetch, weight-prefetch pipeline, no-max softmax, per-head
// norm at O-write, C-in biases, NO_CSE discipline.
__launch_bounds__(256)
__global__ void win_attn(const float* __restrict__ x,
                         const float* __restrict__ qkv_b,
                         const float* __restrict__ proj_b,
                         const short* __restrict__ qkv_wb,
                         const short* __restrict__ proj_wb,
                         const short* __restrict__ bias_bf,
                         float* __restrict__ out) {
  __shared__ __align__(16) char lds[65536];
  char* const ldsA  = lds;
  char* const ldsB  = lds + 16384;
  char* const ldsOA = lds + 32768;
  char* const ldsOB = lds + 49152;

  const int tid  = threadIdx.x;
  const int lane = tid & 63;
  const int w    = tid >> 6;
  const int l15  = lane & 15;
  const int g    = lane >> 4;
  const int winA = blockIdx.x * 2;

  // ---- stage both windows: issue all loads first ----
  const float* xwA = x + (size_t)winA * (NTOK * DIMC);
  const float* xwB = xwA + NTOK * DIMC;
  vf4 aA[4], bA[4], aB[4], bB[4];
  int srow[4], sc16[4];
#pragma unroll
  for (int it = 0; it < 4; ++it) {
    int chunk = tid + it * 256;
    srow[it] = chunk >> 4; sc16[it] = chunk & 15;
    if (srow[it] < NTOK) {
      const float* sA = xwA + srow[it] * DIMC + sc16[it] * 8;
      const float* sB = xwB + srow[it] * DIMC + sc16[it] * 8;
      aA[it] = *(const vf4*)sA; bA[it] = *(const vf4*)(sA + 4);
      aB[it] = *(const vf4*)sB; bB[it] = *(const vf4*)(sB + 4);
    }
  }

  // ---- QK-dt0 weights+biases issued HERE: latency hides under staging ----
  vs8 bwQ[4], bwK[4];
  vf4 qbQ, qbK;
  {
    const short* wrQ = qkv_wb + ((2 * w) * 16 + l15) * DIMC;
    const short* wrK = qkv_wb + ((8 + 2 * w) * 16 + l15) * DIMC;
#pragma unroll
    for (int kk = 0; kk < 4; ++kk) {
      bwQ[kk] = *(const vs8*)(wrQ + kk * 32 + g * 8);
      bwK[kk] = *(const vs8*)(wrK + kk * 32 + g * 8);
    }
    qbQ = *(const vf4*)(qkv_b + (2 * w) * 16 + g * 4);
    qbK = *(const vf4*)(qkv_b + (8 + 2 * w) * 16 + g * 4);
  }

  // ---- convert + write staging ----
#pragma unroll
  for (int it = 0; it < 4; ++it) {
    union { vs8 s; unsigned u[4]; } pA, pB;
    if (srow[it] < NTOK) {
      pA.u[0] = cvtpk(aA[it].x, aA[it].y); pA.u[1] = cvtpk(aA[it].z, aA[it].w);
      pA.u[2] = cvtpk(bA[it].x, bA[it].y); pA.u[3] = cvtpk(bA[it].z, bA[it].w);
      pB.u[0] = cvtpk(aB[it].x, aB[it].y); pB.u[1] = cvtpk(aB[it].z, aB[it].w);
      pB.u[2] = cvtpk(bB[it].x, bB[it].y); pB.u[3] = cvtpk(bB[it].z, bB[it].w);
    } else {
      pA.u[0] = pA.u[1] = pA.u[2] = pA.u[3] = 0u;
      pB.u[0] = pB.u[1] = pB.u[2] = pB.u[3] = 0u;
    }
    int off = srow[it] * 256 + ((sc16[it] * 16) ^ SWZ(srow[it]));
    *(vs8*)(ldsA + off) = pA.s;
    *(vs8*)(ldsB + off) = pB.s;
  }
  __syncthreads();  // barrier-1: staged X visible

  // ---- GEMM1: 4 passes (QK-dt0, V-dt0, QK-dt1, V-dt1), shared frag reads ----
  vh4 qB[2][4], qBB[2][4], kA[2][4], kAB[2][4], vA[2][4], vAB[2][4];
  const float QSC2 = QK_SCALE * LOG2E;
  vs8 bwV[4];
  float bvV;
#pragma unroll
  for (int dt = 0; dt < 2; ++dt) {
    {
      const int cV = 16 + 2 * w + dt;
      const short* wr = qkv_wb + (cV * 16 + l15) * DIMC;
#pragma unroll
      for (int kk = 0; kk < 4; ++kk) bwV[kk] = *(const vs8*)(wr + kk * 32 + g * 8);
      bvV = qkv_b[cV * 16 + l15];
    }
    NO_CSE();
    {  // QK pass: one frag read feeds Q and K MFMAs of both windows
      vf4 aQ[2][4], aK[2][4];
#pragma unroll
      for (int tr = 0; tr < 4; ++tr) {
        aQ[0][tr] = qbQ; aQ[1][tr] = qbQ;
        aK[0][tr] = qbK; aK[1][tr] = qbK;
      }
      __builtin_amdgcn_s_setprio(1);
#pragma unroll
      for (int kk = 0; kk < 4; ++kk)
#pragma unroll
        for (int tr = 0; tr < 4; ++tr) {
          int row = tr * 16 + l15;
          int off = row * 256 + ((kk * 64 + g * 16) ^ SWZ(row));
          vs8 fA = *(const vs8*)(ldsA + off);
          vs8 fB = *(const vs8*)(ldsB + off);
          aQ[0][tr] = __builtin_amdgcn_mfma_f32_16x16x32_bf16(bwQ[kk], fA, aQ[0][tr], 0, 0, 0);
          aK[0][tr] = __builtin_amdgcn_mfma_f32_16x16x32_bf16(bwK[kk], fA, aK[0][tr], 0, 0, 0);
          aQ[1][tr] = __builtin_amdgcn_mfma_f32_16x16x32_bf16(bwQ[kk], fB, aQ[1][tr], 0, 0, 0);
          aK[1][tr] = __builtin_amdgcn_mfma_f32_16x16x32_bf16(bwK[kk], fB, aK[1][tr], 0, 0, 0);
        }
      __builtin_amdgcn_s_setprio(0);
#pragma unroll
      for (int tr = 0; tr < 4; ++tr) {
        qB[dt][tr]  = pack4h(aQ[0][tr][0] * QSC2, aQ[0][tr][1] * QSC2, aQ[0][tr][2] * QSC2, aQ[0][tr][3] * QSC2);
        qBB[dt][tr] = pack4h(aQ[1][tr][0] * QSC2, aQ[1][tr][1] * QSC2, aQ[1][tr][2] * QSC2, aQ[1][tr][3] * QSC2);
        kA[dt][tr]  = pack4h(aK[0][tr][0], aK[0][tr][1], aK[0][tr][2], aK[0][tr][3]);
        kAB[dt][tr] = pack4h(aK[1][tr][0], aK[1][tr][1], aK[1][tr][2], aK[1][tr][3]);
      }
    }
    if (dt == 0) {  // prefetch QK-dt1 weights (hides under V pass)
      const short* wrQ = qkv_wb + ((2 * w + 1) * 16 + l15) * DIMC;
      const short* wrK = qkv_wb + ((8 + 2 * w + 1) * 16 + l15) * DIMC;
#pragma unroll
      for (int kk = 0; kk < 4; ++kk) {
        bwQ[kk] = *(const vs8*)(wrQ + kk * 32 + g * 8);
        bwK[kk] = *(const vs8*)(wrK + kk * 32 + g * 8);
      }
      qbQ = *(const vf4*)(qkv_b + (2 * w + 1) * 16 + g * 4);
      qbK = *(const vf4*)(qkv_b + (8 + 2 * w + 1) * 16 + g * 4);
    }
    NO_CSE();
    {  // V pass (normal orientation)
      vf4 aV[2][4];
#pragma unroll
      for (int tr = 0; tr < 4; ++tr) {
        aV[0][tr] = (vf4){bvV, bvV, bvV, bvV};
        aV[1][tr] = aV[0][tr];
      }
      __builtin_amdgcn_s_setprio(1);
#pragma unroll
      for (int kk = 0; kk < 4; ++kk)
#pragma unroll
        for (int tr = 0; tr < 4; ++tr) {
          int row = tr * 16 + l15;
          int off = row * 256 + ((kk * 64 + g * 16) ^ SWZ(row));
          vs8 fA = *(const vs8*)(ldsA + off);
          vs8 fB = *(const vs8*)(ldsB + off);
          aV[0][tr] = __builtin_amdgcn_mfma_f32_16x16x32_bf16(fA, bwV[kk], aV[0][tr], 0, 0, 0);
          aV[1][tr] = __builtin_amdgcn_mfma_f32_16x16x32_bf16(fB, bwV[kk], aV[1][tr], 0, 0, 0);
        }
      __builtin_amdgcn_s_setprio(0);
#pragma unroll
      for (int tr = 0; tr < 4; ++tr) {
        vA[dt][tr]  = pack4h(aV[0][tr][0], aV[0][tr][1], aV[0][tr][2], aV[0][tr][3]);
        vAB[dt][tr] = pack4h(aV[1][tr][0], aV[1][tr][1], aV[1][tr][2], aV[1][tr][3]);
      }
    }
  }

  // ---- attention fused per q-row-tile (NO barrier needed: O region separate) ----
  const short* bpb = bias_bf + w * 4096;
  vu2 cinC[4];
#pragma unroll
  for (int tcK = 0; tcK < 4; ++tcK)
    cinC[tcK] = *(const vu2*)(bpb + l15 * 64 + tcK * 16 + g * 4);
#pragma unroll
  for (int trQ = 0; trQ < 4; ++trQ) {
    const int q = trQ * 16 + l15;
    vu2 cinN[4];
    if (trQ < 3) {
#pragma unroll
      for (int tcK = 0; tcK < 4; ++tcK)
        cinN[tcK] = *(const vu2*)(bpb + (q + 16) * 64 + tcK * 16 + g * 4);
    }
    const vh8 q8A = cat8(qB[0][trQ], qB[1][trQ]);
    const vh8 q8B = cat8(qBB[0][trQ], qBB[1][trQ]);
    vf4 sA[4], sB[4];
    __builtin_amdgcn_s_setprio(1);
#pragma unroll
    for (int tcK = 0; tcK < 4; ++tcK) {
      vf4 cin = unpack_bf4(cinC[tcK]);  // shared A/B (already *log2e)
      sA[tcK] = __builtin_amdgcn_mfma_f32_16x16x32_f16(cat8(kA[0][tcK], kA[1][tcK]), q8A, cin, 0, 0, 0);
      sB[tcK] = __builtin_amdgcn_mfma_f32_16x16x32_f16(cat8(kAB[0][tcK], kAB[1][tcK]), q8B, cin, 0, 0, 0);
    }
    __builtin_amdgcn_s_setprio(0);
    float sumA = 0.f, sumB = 0.f;
#pragma unroll
    for (int tcK = 0; tcK < 4; ++tcK)
#pragma unroll
      for (int r = 0; r < 4; ++r) {
        float eA = exp2f_raw(sA[tcK][r]); sA[tcK][r] = eA; sumA += eA;
        float eB = exp2f_raw(sB[tcK][r]); sB[tcK][r] = eB; sumB += eB;
      }
    sumA += __shfl_xor(sumA, 16, 64);
    sumB += __shfl_xor(sumB, 16, 64);
    sumA += __shfl_xor(sumA, 32, 64);
    sumB += __shfl_xor(sumB, 32, 64);
    float ivA = 1.0f / sumA, ivB = 1.0f / sumB;
    vh4 pA[4], pB[4];
#pragma unroll
    for (int tcK = 0; tcK < 4; ++tcK) {
      pA[tcK] = pack4h(sA[tcK][0], sA[tcK][1], sA[tcK][2], sA[tcK][3]);
      pB[tcK] = pack4h(sB[tcK][0], sB[tcK][1], sB[tcK][2], sB[tcK][3]);
    }
    vf4 o0A = (vf4){0.f,0.f,0.f,0.f}, o1A = o0A, o0B = o0A, o1B = o0A;
    __builtin_amdgcn_s_setprio(1);
#pragma unroll
    for (int tp = 0; tp < 2; ++tp) {
      const vh8 p8A = cat8(pA[2 * tp], pA[2 * tp + 1]);
      const vh8 p8B = cat8(pB[2 * tp], pB[2 * tp + 1]);
      o0A = __builtin_amdgcn_mfma_f32_16x16x32_f16(cat8(vA[0][2 * tp], vA[0][2 * tp + 1]), p8A, o0A, 0, 0, 0);
      o0B = __builtin_amdgcn_mfma_f32_16x16x32_f16(cat8(vAB[0][2 * tp], vAB[0][2 * tp + 1]), p8B, o0B, 0, 0, 0);
      o1A = __builtin_amdgcn_mfma_f32_16x16x32_f16(cat8(vA[1][2 * tp], vA[1][2 * tp + 1]), p8A, o1A, 0, 0, 0);
      o1B = __builtin_amdgcn_mfma_f32_16x16x32_f16(cat8(vAB[1][2 * tp], vAB[1][2 * tp + 1]), p8B, o1B, 0, 0, 0);
    }
    __builtin_amdgcn_s_setprio(0);
    {
      int db0 = (w * 32 + g * 4) * 2;
      int db1 = (w * 32 + 16 + g * 4) * 2;
      int o0 = q * 256 + (db0 ^ SWZ(q));
      int o1 = q * 256 + (db1 ^ SWZ(q));
      vu2 p;
      p[0] = cvtpk(o0A[0] * ivA, o0A[1] * ivA); p[1] = cvtpk(o0A[2] * ivA, o0A[3] * ivA);
      *(vu2*)(ldsOA + o0) = p;
      p[0] = cvtpk(o1A[0] * ivA, o1A[1] * ivA); p[1] = cvtpk(o1A[2] * ivA, o1A[3] * ivA);
      *(vu2*)(ldsOA + o1) = p;
      p[0] = cvtpk(o0B[0] * ivB, o0B[1] * ivB); p[1] = cvtpk(o0B[2] * ivB, o0B[3] * ivB);
      *(vu2*)(ldsOB + o0) = p;
      p[0] = cvtpk(o1B[0] * ivB, o1B[1] * ivB); p[1] = cvtpk(o1B[2] * ivB, o1B[3] * ivB);
      *(vu2*)(ldsOB + o1) = p;
    }
#pragma unroll
    for (int tcK = 0; tcK < 4; ++tcK) cinC[tcK] = cinN[tcK];
  }

  // ---- GEMM2 weights/bias loaded BEFORE the barrier (latency hides under it) ----
  vs8 bw2[2][4];
  vf4 pb2[2];
#pragma unroll
  for (int ci = 0; ci < 2; ++ci) {
    int ct = w + ci * 4;
    const short* wr = proj_wb + (ct * 16 + l15) * DIMC;
#pragma unroll
    for (int kk = 0; kk < 4; ++kk) bw2[ci][kk] = *(const vs8*)(wr + kk * 32 + g * 8);
    pb2[ci] = *(const vf4*)(proj_b + ct * 16 + g * 4);
  }
  __syncthreads();  // barrier-2: all O visible

  // ---- GEMM2 (swapped), both ci fused: one frag read feeds 2 MFMAs ----
  float* outA = out + (size_t)winA * (NTOK * DIMC);
  float* outB = outA + NTOK * DIMC;
  {
    NO_CSE();
    vf4 acc[2][2][4];  // [ci][win][tr]
#pragma unroll
    for (int ci = 0; ci < 2; ++ci)
#pragma unroll
      for (int tr = 0; tr < 4; ++tr) { acc[ci][0][tr] = pb2[ci]; acc[ci][1][tr] = pb2[ci]; }
    __builtin_amdgcn_s_setprio(1);
#pragma unroll
    for (int kk = 0; kk < 4; ++kk)
#pragma unroll
      for (int tr = 0; tr < 4; ++tr) {
        int row = tr * 16 + l15;
        int off = row * 256 + ((kk * 64 + g * 16) ^ SWZ(row));
        vs8 fA = *(const vs8*)(ldsOA + off);
        vs8 fB = *(const vs8*)(ldsOB + off);
        acc[0][0][tr] = __builtin_amdgcn_mfma_f32_16x16x32_bf16(bw2[0][kk], fA, acc[0][0][tr], 0, 0, 0);
        acc[1][0][tr] = __builtin_amdgcn_mfma_f32_16x16x32_bf16(bw2[1][kk], fA, acc[1][0][tr], 0, 0, 0);
        acc[0][1][tr] = __builtin_amdgcn_mfma_f32_16x16x32_bf16(bw2[0][kk], fB, acc[0][1][tr], 0, 0, 0);
        acc[1][1][tr] = __builtin_amdgcn_mfma_f32_16x16x32_bf16(bw2[1][kk], fB, acc[1][1][tr], 0, 0, 0);
      }
    __builtin_amdgcn_s_setprio(0);
#pragma unroll
    for (int ci = 0; ci < 2; ++ci) {
      int ct = w + ci * 4;
#pragma unroll
      for (int tr = 0; tr < 4; ++tr) {
        int token = tr * 16 + l15;
        if (token < NTOK) {
          *(vf4*)(outA + token * DIMC + ct * 16 + g * 4) = acc[ci][0][tr];
          *(vf4*)(outB + token * DIMC + ct * 16 + g * 4) = acc[ci][1][tr];
        }
      }
    }
  }
}

extern "C" void kernel_launch(void* const* d_in, const int* in_sizes, int n_in,
                              void* d_out, int out_size, void* d_ws, size_t ws_size,
                              hipStream_t stream) {
  const float* x          = (const float*)d_in[0];
  const float* qkv_w      = (const float*)d_in[1];
  const float* qkv_b      = (const float*)d_in[2];
  const float* proj_w     = (const float*)d_in[3];
  const float* proj_b     = (const float*)d_in[4];
  const float* bias_table = (const float*)d_in[5];
  const int*   rel_index  = (const int*)d_in[6];
  float* out = (float*)d_out;

  short* qkv_wb   = (short*)d_ws;                      // 49152 bf16
  short* proj_wb  = (short*)((char*)d_ws + 98304);     // 16384 bf16
  short* bias_bf  = (short*)((char*)d_ws + 131072);    // 4*64*64 bf16 = 32KB

  prep_kernel<<<320, 256, 0, stream>>>(qkv_w, proj_w, bias_table, rel_index,
                                       qkv_wb, proj_wb, bias_bf);
  win_attn<<<NWIN / 2, 256, 0, stream>>>(x, qkv_b, proj_b, qkv_wb, proj_wb, bias_bf, out);
}